// Round 1
// baseline (77696.570 us; speedup 1.0000x reference)
//
#include <hip/hip_runtime.h>
#include <hip/hip_cooperative_groups.h>

namespace cg = cooperative_groups;

typedef _Float16 half8 __attribute__((ext_vector_type(8)));
typedef float floatx4 __attribute__((ext_vector_type(4)));

#define B_ 64
#define S_ 512
#define H_ 1024

__device__ __forceinline__ float sigmoidf_(float x) { return 1.0f / (1.0f + __expf(-x)); }

// Persistent cooperative scan kernel.
// Grid: 256 blocks x 256 threads (1 block/CU).
// Block (c = bid&63, q = bid>>6): owns H-columns [16c,16c+16) and K-quarter q
// for the GEMM; owns batches [16q,16q+16) x cols [16c,16c+16) for elementwise.
// Wave m (0..3) = M-tile (batches 16m..16m+15) of the partial GEMM.
// Weights (3 gates x 16 cols x 256 k, f16) persist in registers (96 VGPR/lane).
__global__ void __launch_bounds__(256, 1)
lstm_scan(const float* __restrict__ emb, const float* __restrict__ W, const float* __restrict__ bW,
          const float* __restrict__ U, const float* __restrict__ bU,
          const float* __restrict__ V, const float* __restrict__ bV,
          float* __restrict__ out, unsigned char* __restrict__ ws)
{
    cg::grid_group grid = cg::this_grid();
    const int bid  = blockIdx.x;
    const int c    = bid & 63;   // column group (16 H-cols)
    const int q    = bid >> 6;   // K-quarter (256 k) / batch tile for elementwise
    const int tid  = threadIdx.x;
    const int lane = tid & 63;
    const int m    = tid >> 6;   // wave id = M-tile
    const int ncol = lane & 15;  // frag row/col index
    const int kgrp = lane >> 4;  // frag k-block

    _Float16* xi_buf = (_Float16*)ws;                                   // [2][64][1024] f16
    float*    part   = (float*)(ws + 2 * B_ * H_ * sizeof(_Float16));   // [4 q][64 c][3 g][4 m][64 l][4 r] f32

    // ---- load persistent B fragments (weights -> f16, registers) ----
    // B-frag for mfma_f32_16x16x32_f16: lane l holds B[k=(l>>4)*8+e][n=l&15],
    // i.e. 8 contiguous k of weight row (16c + (l&15)).
    half8 Bf[3][8];
    {
        const int wrow  = c * 16 + ncol;
        const int kbase = q * 256 + kgrp * 8;
        const float* Wp0 = W + wrow * H_ + kbase;
        const float* Wp1 = U + wrow * H_ + kbase;
        const float* Wp2 = V + wrow * H_ + kbase;
        #pragma unroll
        for (int ks = 0; ks < 8; ++ks) {
            half8 h0, h1, h2;
            #pragma unroll
            for (int e = 0; e < 8; ++e) {
                h0[e] = (_Float16)Wp0[ks * 32 + e];
                h1[e] = (_Float16)Wp1[ks * 32 + e];
                h2[e] = (_Float16)Wp2[ks * 32 + e];
            }
            Bf[0][ks] = h0; Bf[1][ks] = h1; Bf[2][ks] = h2;
        }
    }

    // ---- elementwise ownership: thread -> (b, j) ----
    const int row  = tid >> 4;        // 0..15
    const int colx = tid & 15;        // 0..15
    const int b    = q * 16 + row;
    const int j    = c * 16 + colx;
    const float bw = bW[j], bu = bU[j], bv = bV[j];
    // map (row,colx) -> (lane,reg) of the C/D layout: row = (l>>4)*4 + r, col = l&15
    const int lr_l = ((row >> 2) << 4) | colx;
    const int lr_r = row & 3;

    float p1s = 0.0f;                                 // persistent cell state
    float xio = emb[(b * S_ + 0) * H_ + j];           // fp32 copy of own xi (p2 init = 0)
    xi_buf[0 * B_ * H_ + b * H_ + j] = (_Float16)xio;

    __threadfence();
    grid.sync();

    // part strides: r=1, l=4, m=256, g=1024, c=3072, q=196608 (floats)
    float* wr_base = part + (((q * 64 + c) * 3 + 0) * 4 + m) * 256 + lane * 4;
    const int rd_off = (((0 * 64 + c) * 3 + 0) * 4 + q) * 256 + lr_l * 4 + lr_r;

    for (int t = 0; t < S_; ++t) {
        // prefetch next step's emb early (hides HBM latency under phase A + sync)
        float embn = 0.0f;
        if (t + 1 < S_) embn = emb[(b * S_ + (t + 1)) * H_ + j];

        // ---- Phase A: partial GEMM (this K-quarter) via MFMA ----
        const _Float16* xs   = xi_buf + (t & 1) * B_ * H_;
        const _Float16* arow = xs + (m * 16 + ncol) * H_ + q * 256 + kgrp * 8;
        floatx4 a0 = {0.f, 0.f, 0.f, 0.f};
        floatx4 a1 = {0.f, 0.f, 0.f, 0.f};
        floatx4 a2 = {0.f, 0.f, 0.f, 0.f};
        #pragma unroll
        for (int ks = 0; ks < 8; ++ks) {
            half8 a = *(const half8*)(arow + ks * 32);
            a0 = __builtin_amdgcn_mfma_f32_16x16x32_f16(a, Bf[0][ks], a0, 0, 0, 0);
            a1 = __builtin_amdgcn_mfma_f32_16x16x32_f16(a, Bf[1][ks], a1, 0, 0, 0);
            a2 = __builtin_amdgcn_mfma_f32_16x16x32_f16(a, Bf[2][ks], a2, 0, 0, 0);
        }
        *(floatx4*)(wr_base)        = a0;   // gate f partial
        *(floatx4*)(wr_base + 1024) = a1;   // gate i partial
        *(floatx4*)(wr_base + 2048) = a2;   // gate g partial

        __threadfence();
        grid.sync();
        __threadfence();

        // ---- Phase B: reduce K-quarters + gates + state update ----
        float pf = 0.f, pu = 0.f, pv = 0.f;
        #pragma unroll
        for (int qp = 0; qp < 4; ++qp) {
            const float* rp = part + qp * 196608 + rd_off;
            pf += rp[0];
            pu += rp[1024];
            pv += rp[2048];
        }
        float fg = sigmoidf_(pf + bw);
        float ig = sigmoidf_(pu + bu);
        float gg = tanhf(pv + bv);
        p1s = fg * p1s + ig * gg;
        float p2 = sigmoidf_(xio) * tanhf(p1s);
        out[(b * S_ + t) * H_ + j] = p2;
        if (t + 1 < S_) {
            float xin = embn + p2;
            xio = xin;
            xi_buf[((t + 1) & 1) * B_ * H_ + b * H_ + j] = (_Float16)xin;
        }

        __threadfence();
        grid.sync();
        __threadfence();
    }
}

extern "C" void kernel_launch(void* const* d_in, const int* in_sizes, int n_in,
                              void* d_out, int out_size, void* d_ws, size_t ws_size,
                              hipStream_t stream)
{
    const float* emb = (const float*)d_in[0];
    const float* W   = (const float*)d_in[1];
    const float* bWv = (const float*)d_in[2];
    const float* U   = (const float*)d_in[3];
    const float* bUv = (const float*)d_in[4];
    const float* V   = (const float*)d_in[5];
    const float* bVv = (const float*)d_in[6];
    float* outp = (float*)d_out;
    unsigned char* ws = (unsigned char*)d_ws;

    void* args[] = {(void*)&emb, (void*)&W, (void*)&bWv, (void*)&U, (void*)&bUv,
                    (void*)&V, (void*)&bVv, (void*)&outp, (void*)&ws};
    (void)in_sizes; (void)n_in; (void)out_size; (void)ws_size;

    hipLaunchCooperativeKernel((const void*)lstm_scan, dim3(256), dim3(256),
                               args, 0, stream);
}

// Round 4
// 36575.171 us; speedup vs baseline: 2.1243x; 2.1243x over previous
//
#include <hip/hip_runtime.h>
#include <hip/hip_cooperative_groups.h>

namespace cg = cooperative_groups;

typedef _Float16 half8 __attribute__((ext_vector_type(8)));
typedef float floatx4 __attribute__((ext_vector_type(4)));

#define B_ 64
#define S_ 512
#define H_ 1024

__device__ __forceinline__ float sigmoidf_(float x) { return 1.0f / (1.0f + __expf(-x)); }

// 256 blocks x 256 threads (EXACT round-1 launch envelope, which is proven to
// launch cooperatively). Block (cb = bid&63, mb = bid>>6) owns the 16x16
// output tile: batches [16mb,16mb+16) x cols [16cb,16cb+16), FULL K=1024.
// Wave w = K-quarter [256w, 256w+256). K-reduction in LDS (12 KB).
// ONE grid sync per step (double-buffered xi makes it sufficient).
__global__ void __launch_bounds__(256, 1)
lstm_scan(const float* __restrict__ emb, const float* __restrict__ W, const float* __restrict__ bW,
          const float* __restrict__ U, const float* __restrict__ bU,
          const float* __restrict__ V, const float* __restrict__ bV,
          float* __restrict__ out, unsigned char* __restrict__ ws)
{
    cg::grid_group grid = cg::this_grid();
    const int bid  = blockIdx.x;
    const int cb   = bid & 63;    // column group (16 H-cols)
    const int mb   = bid >> 6;    // batch group (16 batches)
    const int tid  = threadIdx.x;
    const int w    = tid >> 6;    // wave id = K-quarter
    const int lane = tid & 63;
    const int fr   = lane & 15;   // frag row/col index
    const int kg   = lane >> 4;   // frag k-block

    _Float16* xi_buf = (_Float16*)ws;   // [2][64][1024] f16

    // LDS partials: [wave][gate][lane][4] f32 = 12 KB
    __shared__ __align__(16) float part[4 * 3 * 64 * 4];

    // ---- persistent weight fragments (f16, registers): 3 gates x 8 ksteps ----
    // B-frag of mfma_f32_16x16x32_f16: lane l holds B[k=(l>>4)*8+e][n=l&15],
    // B[k][n] = Wgate[jabs = 16*cb + n][k].  (Layout proven in round 1.)
    half8 Bf[3][8];
    {
        const int jrow = cb * 16 + fr;
        const int kb   = w * 256 + kg * 8;
        const float* p0 = W + jrow * H_ + kb;
        const float* p1 = U + jrow * H_ + kb;
        const float* p2 = V + jrow * H_ + kb;
        #pragma unroll
        for (int ks = 0; ks < 8; ++ks) {
            half8 h0, h1, h2;
            #pragma unroll
            for (int e = 0; e < 8; ++e) {
                h0[e] = (_Float16)p0[ks * 32 + e];
                h1[e] = (_Float16)p1[ks * 32 + e];
                h2[e] = (_Float16)p2[ks * 32 + e];
            }
            Bf[0][ks] = h0; Bf[1][ks] = h1; Bf[2][ks] = h2;
        }
    }

    // ---- elementwise ownership: thread -> ONE cell (b, j) ----
    const int rt = tid >> 4;           // row in tile 0..15
    const int ct = tid & 15;           // col in tile 0..15
    const int b  = mb * 16 + rt;
    const int j  = cb * 16 + ct;
    const float bw = bW[j], bu = bU[j], bv = bV[j];
    // C/D layout (proven): col = lane&15, row = (lane>>4)*4 + reg
    const int rl = (rt >> 2) * 16 + ct;   // source lane
    const int rr = rt & 3;                // source reg

    float p1s = 0.0f;
    float xio = emb[(b * S_ + 0) * H_ + j];      // p2 init = 0
    xi_buf[b * H_ + j] = (_Float16)xio;

    __threadfence();
    grid.sync();
    __threadfence();

    for (int t = 0; t < S_; ++t) {
        const _Float16* xs = xi_buf + (t & 1) * B_ * H_;
        _Float16*       xd = xi_buf + ((t + 1) & 1) * B_ * H_;

        // prefetch next step's emb (hides HBM latency under MFMA + reduce)
        float embn = 0.0f;
        if (t + 1 < S_) embn = emb[(b * S_ + t + 1) * H_ + j];

        // ---- MFMA: this wave's K-quarter, one 16x16 tile, 3 gates ----
        floatx4 a0 = {0.f, 0.f, 0.f, 0.f};
        floatx4 a1 = {0.f, 0.f, 0.f, 0.f};
        floatx4 a2 = {0.f, 0.f, 0.f, 0.f};
        const _Float16* ab = xs + (mb * 16 + fr) * H_ + w * 256 + kg * 8;
        #pragma unroll
        for (int ks = 0; ks < 8; ++ks) {
            half8 a = *(const half8*)(ab + ks * 32);
            a0 = __builtin_amdgcn_mfma_f32_16x16x32_f16(a, Bf[0][ks], a0, 0, 0, 0);
            a1 = __builtin_amdgcn_mfma_f32_16x16x32_f16(a, Bf[1][ks], a1, 0, 0, 0);
            a2 = __builtin_amdgcn_mfma_f32_16x16x32_f16(a, Bf[2][ks], a2, 0, 0, 0);
        }

        // ---- K-reduction in LDS ----
        *(floatx4*)&part[((w * 3 + 0) * 64 + lane) * 4] = a0;
        *(floatx4*)&part[((w * 3 + 1) * 64 + lane) * 4] = a1;
        *(floatx4*)&part[((w * 3 + 2) * 64 + lane) * 4] = a2;
        __syncthreads();

        float pf = bw, pu = bu, pv = bv;
        #pragma unroll
        for (int wv = 0; wv < 4; ++wv) {
            pf += part[((wv * 3 + 0) * 64 + rl) * 4 + rr];
            pu += part[((wv * 3 + 1) * 64 + rl) * 4 + rr];
            pv += part[((wv * 3 + 2) * 64 + rl) * 4 + rr];
        }

        // ---- gates + state update + writes ----
        float fg = sigmoidf_(pf);
        float ig = sigmoidf_(pu);
        float gg = tanhf(pv);
        p1s = fg * p1s + ig * gg;
        float p2 = sigmoidf_(xio) * tanhf(p1s);
        out[(b * S_ + t) * H_ + j] = p2;
        if (t + 1 < S_) {
            float xin = embn + p2;
            xio = xin;
            xd[b * H_ + j] = (_Float16)xin;
        }

        // ---- ONE grid barrier per step (round-1-proven fence+sync+fence).
        // It also orders the LDS read(t) -> write(t+1) across the block, since
        // no thread passes the grid barrier until all threads arrived.
        __threadfence();
        grid.sync();
        __threadfence();
    }
}

extern "C" void kernel_launch(void* const* d_in, const int* in_sizes, int n_in,
                              void* d_out, int out_size, void* d_ws, size_t ws_size,
                              hipStream_t stream)
{
    const float* emb = (const float*)d_in[0];
    const float* W   = (const float*)d_in[1];
    const float* bWv = (const float*)d_in[2];
    const float* U   = (const float*)d_in[3];
    const float* bUv = (const float*)d_in[4];
    const float* V   = (const float*)d_in[5];
    const float* bVv = (const float*)d_in[6];
    float* outp = (float*)d_out;
    unsigned char* ws = (unsigned char*)d_ws;
    (void)in_sizes; (void)n_in; (void)out_size; (void)ws_size;

    void* args[] = {(void*)&emb, (void*)&W, (void*)&bWv, (void*)&U, (void*)&bUv,
                    (void*)&V, (void*)&bVv, (void*)&outp, (void*)&ws};
    hipLaunchCooperativeKernel((const void*)lstm_scan, dim3(256), dim3(256),
                               args, 0, stream);
}

// Round 5
// 11300.916 us; speedup vs baseline: 6.8752x; 3.2365x over previous
//
#include <hip/hip_runtime.h>

typedef _Float16 half8 __attribute__((ext_vector_type(8)));
typedef float floatx4 __attribute__((ext_vector_type(4)));

#define B_ 64
#define S_ 512
#define H_ 1024

// Per-group barrier state in module .bss: zero-initialized at load, NOT part
// of d_ws (so the harness's 0xAA poison never touches it). barA returns to 0
// at the end of every launch; barE grows monotonically and is handled by the
// per-launch epoch base E0.
__device__ unsigned barA[4 * 64];   // arrival counters, group g at [g*64]
__device__ unsigned barE[4 * 64];   // release epochs,   group g at [g*64]

__device__ __forceinline__ float sigmoidf_(float x) { return 1.0f / (1.0f + __expf(-x)); }
__device__ __forceinline__ float tanhf_(float x) {
    // tanh(x) = 1 - 2/(e^{2x}+1); __expf handles +-inf saturation correctly.
    return 1.0f - 2.0f / (__expf(2.0f * x) + 1.0f);
}

// 256 blocks x 256 threads (round-1/4 proven cooperative envelope).
// Block (cb = bid&63, mb = bid>>6) owns the 16x16 output tile:
// batches [16mb,16mb+16) x cols [16cb,16cb+16), FULL K=1024.
// Wave w = K-quarter. K-reduction in LDS (12 KB).
// Dependency graph is block-diagonal in mb: block (cb,mb) reads xi only for
// batches of group mb and writes xi only for batches of group mb. So each of
// the 4 groups of 64 blocks syncs independently (cheap 64-arrival barrier).
__global__ void __launch_bounds__(256, 1)
lstm_scan(const float* __restrict__ emb, const float* __restrict__ W, const float* __restrict__ bW,
          const float* __restrict__ U, const float* __restrict__ bU,
          const float* __restrict__ V, const float* __restrict__ bV,
          float* __restrict__ out, unsigned char* __restrict__ ws)
{
    const int bid  = blockIdx.x;
    const int cb   = bid & 63;    // column group (16 H-cols)
    const int mb   = bid >> 6;    // batch group (16 batches) == barrier group
    const int tid  = threadIdx.x;
    const int w    = tid >> 6;    // wave id = K-quarter
    const int lane = tid & 63;
    const int fr   = lane & 15;   // frag row/col index
    const int kg   = lane >> 4;   // frag k-block

    _Float16* xi_buf = (_Float16*)ws;   // [2][64][1024] f16

    // LDS partials: [wave][gate][lane][4] f32 = 12 KB
    __shared__ __align__(16) float part[4 * 3 * 64 * 4];

    // ---- persistent weight fragments (f16, registers): 3 gates x 8 ksteps ----
    // B-frag of mfma_f32_16x16x32_f16: lane l holds B[k=(l>>4)*8+e][n=l&15],
    // B[k][n] = Wgate[jabs = 16*cb + n][k].  (Layout proven rounds 1 & 4.)
    half8 Bf[3][8];
    {
        const int jrow = cb * 16 + fr;
        const int kb   = w * 256 + kg * 8;
        const float* p0 = W + jrow * H_ + kb;
        const float* p1 = U + jrow * H_ + kb;
        const float* p2 = V + jrow * H_ + kb;
        #pragma unroll
        for (int ks = 0; ks < 8; ++ks) {
            half8 h0, h1, h2;
            #pragma unroll
            for (int e = 0; e < 8; ++e) {
                h0[e] = (_Float16)p0[ks * 32 + e];
                h1[e] = (_Float16)p1[ks * 32 + e];
                h2[e] = (_Float16)p2[ks * 32 + e];
            }
            Bf[0][ks] = h0; Bf[1][ks] = h1; Bf[2][ks] = h2;
        }
    }

    // ---- elementwise ownership: thread -> ONE cell (b, j) ----
    const int rt = tid >> 4;           // row in tile 0..15
    const int ct = tid & 15;           // col in tile 0..15
    const int b  = mb * 16 + rt;
    const int j  = cb * 16 + ct;
    const float bw = bW[j], bu = bU[j], bv = bV[j];
    // C/D layout (proven): col = lane&15, row = (lane>>4)*4 + reg
    const int rl = (rt >> 2) * 16 + ct;   // source lane
    const int rr = rt & 3;                // source reg

    // ---- epoch base: read BEFORE first arrival (all blocks of the group
    // read it before any block can bump barE -> consistent across the group;
    // makes the barrier correct for any starting barE value, i.e. replays).
    unsigned E0 = 0;
    if (tid == 0)
        E0 = __hip_atomic_load(&barE[mb * 64], __ATOMIC_RELAXED, __HIP_MEMORY_SCOPE_AGENT);

    // ---- lean per-group barrier (64 arrivals), proven fence placement ----
    auto gbar = [&](unsigned target) {
        __syncthreads();                       // all block stores drained
        if (tid == 0) {
            __threadfence();                   // release: dirty L2 -> LLC
            unsigned old = __hip_atomic_fetch_add(&barA[mb * 64], 1u,
                               __ATOMIC_RELAXED, __HIP_MEMORY_SCOPE_AGENT);
            if (old == 63u) {
                __hip_atomic_store(&barA[mb * 64], 0u,
                                   __ATOMIC_RELAXED, __HIP_MEMORY_SCOPE_AGENT);
                __hip_atomic_fetch_add(&barE[mb * 64], 1u,
                                       __ATOMIC_RELEASE, __HIP_MEMORY_SCOPE_AGENT);
            } else {
                while ((__hip_atomic_load(&barE[mb * 64], __ATOMIC_ACQUIRE,
                                          __HIP_MEMORY_SCOPE_AGENT) - E0) < target)
                    __builtin_amdgcn_s_sleep(1);
            }
            __threadfence();                   // acquire: invalidate stale L2
        }
        __syncthreads();
    };

    float p1s = 0.0f;
    float xio = emb[(b * S_ + 0) * H_ + j];      // p2 init = 0
    xi_buf[b * H_ + j] = (_Float16)xio;

    gbar(1u);

    for (int t = 0; t < S_; ++t) {
        const _Float16* xs = xi_buf + (t & 1) * B_ * H_;
        _Float16*       xd = xi_buf + ((t + 1) & 1) * B_ * H_;

        // prefetch next step's emb (hides latency under MFMA + reduce)
        float embn = 0.0f;
        if (t + 1 < S_) embn = emb[(b * S_ + t + 1) * H_ + j];

        // ---- MFMA: this wave's K-quarter, one 16x16 tile, 3 gates ----
        floatx4 a0 = {0.f, 0.f, 0.f, 0.f};
        floatx4 a1 = {0.f, 0.f, 0.f, 0.f};
        floatx4 a2 = {0.f, 0.f, 0.f, 0.f};
        const _Float16* ab = xs + (mb * 16 + fr) * H_ + w * 256 + kg * 8;
        #pragma unroll
        for (int ks = 0; ks < 8; ++ks) {
            half8 a = *(const half8*)(ab + ks * 32);
            a0 = __builtin_amdgcn_mfma_f32_16x16x32_f16(a, Bf[0][ks], a0, 0, 0, 0);
            a1 = __builtin_amdgcn_mfma_f32_16x16x32_f16(a, Bf[1][ks], a1, 0, 0, 0);
            a2 = __builtin_amdgcn_mfma_f32_16x16x32_f16(a, Bf[2][ks], a2, 0, 0, 0);
        }

        // ---- K-reduction in LDS ----
        *(floatx4*)&part[((w * 3 + 0) * 64 + lane) * 4] = a0;
        *(floatx4*)&part[((w * 3 + 1) * 64 + lane) * 4] = a1;
        *(floatx4*)&part[((w * 3 + 2) * 64 + lane) * 4] = a2;
        __syncthreads();

        float pf = bw, pu = bu, pv = bv;
        #pragma unroll
        for (int wv = 0; wv < 4; ++wv) {
            pf += part[((wv * 3 + 0) * 64 + rl) * 4 + rr];
            pu += part[((wv * 3 + 1) * 64 + rl) * 4 + rr];
            pv += part[((wv * 3 + 2) * 64 + rl) * 4 + rr];
        }

        // ---- gates + state update + writes ----
        float fg = sigmoidf_(pf);
        float ig = sigmoidf_(pu);
        float gg = tanhf_(pv);
        p1s = fg * p1s + ig * gg;
        float p2 = sigmoidf_(xio) * tanhf_(p1s);
        out[(b * S_ + t) * H_ + j] = p2;

        if (t + 1 < S_) {
            float xin = embn + p2;
            xio = xin;
            xd[b * H_ + j] = (_Float16)xin;
            // ---- ONE per-group barrier per step ----
            gbar((unsigned)(t + 2));
        }
    }
}

extern "C" void kernel_launch(void* const* d_in, const int* in_sizes, int n_in,
                              void* d_out, int out_size, void* d_ws, size_t ws_size,
                              hipStream_t stream)
{
    const float* emb = (const float*)d_in[0];
    const float* W   = (const float*)d_in[1];
    const float* bWv = (const float*)d_in[2];
    const float* U   = (const float*)d_in[3];
    const float* bUv = (const float*)d_in[4];
    const float* V   = (const float*)d_in[5];
    const float* bVv = (const float*)d_in[6];
    float* outp = (float*)d_out;
    unsigned char* ws = (unsigned char*)d_ws;
    (void)in_sizes; (void)n_in; (void)out_size; (void)ws_size;

    void* args[] = {(void*)&emb, (void*)&W, (void*)&bWv, (void*)&U, (void*)&bUv,
                    (void*)&V, (void*)&bVv, (void*)&outp, (void*)&ws};
    hipLaunchCooperativeKernel((const void*)lstm_scan, dim3(256), dim3(256),
                               args, 0, stream);
}

// Round 6
// 9834.243 us; speedup vs baseline: 7.9006x; 1.1491x over previous
//
#include <hip/hip_runtime.h>

typedef _Float16 half8 __attribute__((ext_vector_type(8)));
typedef float floatx4 __attribute__((ext_vector_type(4)));

#define B_ 64
#define S_ 512
#define H_ 1024

// Barrier state in module .bss (zero at load; untouched by ws poison).
// Monotonic: per launch, every slot and every epoch advance by exactly S_.
// Quiescent invariant between launches: slotA[mb][cb] == epochA[mb*32] for
// all cb. Per-launch base e0 is read before any arrival of that launch.
__device__ unsigned slotA[4][64];    // arrival slots (contiguous -> one wave polls all 64)
__device__ unsigned epochA[4 * 32];  // release epoch per group, 128 B apart

__device__ __forceinline__ float sigmoidf_(float x) { return 1.0f / (1.0f + __expf(-x)); }
__device__ __forceinline__ float tanhf_(float x) {
    return 1.0f - 2.0f / (__expf(2.0f * x) + 1.0f);   // saturates correctly via __expf
}

// 256 blocks x 256 threads (proven cooperative envelope). Block (cb=bid&63,
// mb=bid>>6) owns the 16x16 output tile: batches [16mb,16mb+16) x cols
// [16cb,16cb+16), FULL K=1024; wave = K-quarter; K-reduce in LDS (12 KB).
// Groups (mb) are independent -> per-group 64-block barrier.
// Barrier = RMW-free captain barrier: 64 parallel slot stores; root block
// (cb==0) wave0 polls all slots (lane L -> slot[L]); root publishes epoch.
__global__ void __launch_bounds__(256, 1)
lstm_scan(const float* __restrict__ emb, const float* __restrict__ W, const float* __restrict__ bW,
          const float* __restrict__ U, const float* __restrict__ bU,
          const float* __restrict__ V, const float* __restrict__ bV,
          float* __restrict__ out, unsigned char* __restrict__ ws)
{
    const int bid  = blockIdx.x;
    const int cb   = bid & 63;    // column group (16 H-cols)
    const int mb   = bid >> 6;    // batch group == barrier group
    const int tid  = threadIdx.x;
    const int w    = tid >> 6;    // wave id = K-quarter
    const int lane = tid & 63;
    const int fr   = lane & 15;   // frag row/col index
    const int kg   = lane >> 4;   // frag k-block

    _Float16* xi_buf = (_Float16*)ws;   // [2][64][1024] f16

    __shared__ __align__(16) float part[4 * 3 * 64 * 4];   // 12 KB
    __shared__ unsigned sE0;

    // per-launch epoch base: must be read before ANY arrival of this launch.
    // Safe: epochA[mb] only advances after all 64 blocks of the group have
    // arrived, and each block arrives only after reading sE0 (program order).
    if (tid == 0)
        sE0 = __hip_atomic_load(&epochA[mb * 32], __ATOMIC_RELAXED, __HIP_MEMORY_SCOPE_AGENT);
    __syncthreads();
    const unsigned e0 = sE0;

    // ---- persistent weight fragments (f16, registers): 3 gates x 8 ksteps ----
    // B-frag of mfma_f32_16x16x32_f16: lane l holds B[k=(l>>4)*8+e][n=l&15],
    // B[k][n] = Wgate[16*cb + n][k].  (Layout proven rounds 1/4/5.)
    half8 Bf[3][8];
    {
        const int jrow = cb * 16 + fr;
        const int kb   = w * 256 + kg * 8;
        const float* p0 = W + jrow * H_ + kb;
        const float* p1 = U + jrow * H_ + kb;
        const float* p2 = V + jrow * H_ + kb;
        #pragma unroll
        for (int ks = 0; ks < 8; ++ks) {
            half8 h0, h1, h2;
            #pragma unroll
            for (int e = 0; e < 8; ++e) {
                h0[e] = (_Float16)p0[ks * 32 + e];
                h1[e] = (_Float16)p1[ks * 32 + e];
                h2[e] = (_Float16)p2[ks * 32 + e];
            }
            Bf[0][ks] = h0; Bf[1][ks] = h1; Bf[2][ks] = h2;
        }
    }

    // ---- elementwise ownership: thread -> ONE cell (b, j) ----
    const int rt = tid >> 4;
    const int ct = tid & 15;
    const int b  = mb * 16 + rt;
    const int j  = cb * 16 + ct;
    const float bw = bW[j], bu = bU[j], bv = bV[j];
    const int rl = (rt >> 2) * 16 + ct;   // C/D source lane (proven)
    const int rr = rt & 3;                // C/D source reg

    // ---- arrive / wait (split so work can overlap the spin) ----
    auto arrive = [&](unsigned T) {
        __syncthreads();                       // drain this block's stores
        if (tid == 0) {
            __threadfence();                   // release: dirty L2 -> LLC
            __hip_atomic_store(&slotA[mb][cb], e0 + T, __ATOMIC_RELEASE,
                               __HIP_MEMORY_SCOPE_AGENT);
        }
    };
    auto wait = [&](unsigned T) {
        const unsigned tgt = e0 + T;
        if (cb == 0 && tid < 64) {             // root block: wave0 polls all slots
            for (;;) {
                unsigned v = __hip_atomic_load(&slotA[mb][tid], __ATOMIC_RELAXED,
                                               __HIP_MEMORY_SCOPE_AGENT);
                if (__all((int)(v - tgt) >= 0)) break;
                __builtin_amdgcn_s_sleep(1);
            }
            if (tid == 0)
                __hip_atomic_store(&epochA[mb * 32], tgt, __ATOMIC_RELEASE,
                                   __HIP_MEMORY_SCOPE_AGENT);
        }
        if (tid == 0) {
            while ((int)(__hip_atomic_load(&epochA[mb * 32], __ATOMIC_RELAXED,
                                           __HIP_MEMORY_SCOPE_AGENT) - tgt) < 0)
                __builtin_amdgcn_s_sleep(1);
            __threadfence();                   // acquire: invalidate stale L2
        }
        __syncthreads();
    };

    float p1s = 0.0f;
    float xio = emb[(b * S_ + 0) * H_ + j];    // p2 init = 0
    xi_buf[b * H_ + j] = (_Float16)xio;
    float embn = emb[(b * S_ + 1) * H_ + j];   // prefetch for t=0 tail

    arrive(1u);
    wait(1u);

    for (int t = 0; t < S_; ++t) {
        const _Float16* xs = xi_buf + (t & 1) * B_ * H_;
        _Float16*       xd = xi_buf + ((t + 1) & 1) * B_ * H_;

        // ---- MFMA: this wave's K-quarter, one 16x16 tile, 3 gates ----
        floatx4 a0 = {0.f, 0.f, 0.f, 0.f};
        floatx4 a1 = {0.f, 0.f, 0.f, 0.f};
        floatx4 a2 = {0.f, 0.f, 0.f, 0.f};
        const _Float16* ab = xs + (mb * 16 + fr) * H_ + w * 256 + kg * 8;
        #pragma unroll
        for (int ks = 0; ks < 8; ++ks) {
            half8 a = *(const half8*)(ab + ks * 32);
            a0 = __builtin_amdgcn_mfma_f32_16x16x32_f16(a, Bf[0][ks], a0, 0, 0, 0);
            a1 = __builtin_amdgcn_mfma_f32_16x16x32_f16(a, Bf[1][ks], a1, 0, 0, 0);
            a2 = __builtin_amdgcn_mfma_f32_16x16x32_f16(a, Bf[2][ks], a2, 0, 0, 0);
        }

        // ---- K-reduction in LDS ----
        *(floatx4*)&part[((w * 3 + 0) * 64 + lane) * 4] = a0;
        *(floatx4*)&part[((w * 3 + 1) * 64 + lane) * 4] = a1;
        *(floatx4*)&part[((w * 3 + 2) * 64 + lane) * 4] = a2;
        __syncthreads();

        float pf = bw, pu = bu, pv = bv;
        #pragma unroll
        for (int wv = 0; wv < 4; ++wv) {
            pf += part[((wv * 3 + 0) * 64 + rl) * 4 + rr];
            pu += part[((wv * 3 + 1) * 64 + rl) * 4 + rr];
            pv += part[((wv * 3 + 2) * 64 + rl) * 4 + rr];
        }

        // ---- gates + state update ----
        float fg = sigmoidf_(pf);
        float ig = sigmoidf_(pu);
        float gg = tanhf_(pv);
        p1s = fg * p1s + ig * gg;
        float p2 = sigmoidf_(xio) * tanhf_(p1s);

        const bool lastT = (t == S_ - 1);
        if (!lastT) {
            float xin = embn + p2;
            xio = xin;
            xd[b * H_ + j] = (_Float16)xin;    // the only cross-block data
            arrive((unsigned)(t + 2));         // release ASAP
        }

        // ---- overlapped with the spin: out store + next emb prefetch ----
        out[(b * S_ + t) * H_ + j] = p2;
        if (t + 2 < S_) embn = emb[(b * S_ + t + 2) * H_ + j];

        if (!lastT) wait((unsigned)(t + 2));
    }
}

extern "C" void kernel_launch(void* const* d_in, const int* in_sizes, int n_in,
                              void* d_out, int out_size, void* d_ws, size_t ws_size,
                              hipStream_t stream)
{
    const float* emb = (const float*)d_in[0];
    const float* W   = (const float*)d_in[1];
    const float* bWv = (const float*)d_in[2];
    const float* U   = (const float*)d_in[3];
    const float* bUv = (const float*)d_in[4];
    const float* V   = (const float*)d_in[5];
    const float* bVv = (const float*)d_in[6];
    float* outp = (float*)d_out;
    unsigned char* ws = (unsigned char*)d_ws;
    (void)in_sizes; (void)n_in; (void)out_size; (void)ws_size;

    void* args[] = {(void*)&emb, (void*)&W, (void*)&bWv, (void*)&U, (void*)&bUv,
                    (void*)&V, (void*)&bVv, (void*)&outp, (void*)&ws};
    hipLaunchCooperativeKernel((const void*)lstm_scan, dim3(256), dim3(256),
                               args, 0, stream);
}

// Round 7
// 3577.782 us; speedup vs baseline: 21.7164x; 2.7487x over previous
//
#include <hip/hip_runtime.h>

typedef _Float16 half8 __attribute__((ext_vector_type(8)));
typedef float floatx4 __attribute__((ext_vector_type(4)));
typedef unsigned long long u64t;

#define B_ 64
#define S_ 512
#define H_ 1024

// Arrival slots in module .bss (zero at load; never touched by ws poison).
// Monotonic across launches: every slot advances by exactly S_ per launch.
// Per-launch base e0 = own slot value, read before any arrival (all slots are
// equal at quiescence; only the owning block ever writes its slot).
__device__ unsigned slotA[4][64];

__device__ __forceinline__ float sigmoidf_(float x) { return 1.0f / (1.0f + __expf(-x)); }
__device__ __forceinline__ float tanhf_(float x) {
    return 1.0f - 2.0f / (__expf(2.0f * x) + 1.0f);   // saturates correctly via __expf
}

// 256 blocks x 256 threads (proven cooperative envelope). Block (cb=bid&63,
// mb=bid>>6) owns the 16x16 output tile: batches [16mb,16mb+16) x cols
// [16cb,16cb+16), FULL K=1024; wave = K-quarter; K-reduce in LDS.
// ALL cross-block data (xi) moves via agent-scope relaxed atomics (sc1 path:
// write-through to LLC, read-around the non-coherent L2) -> NO threadfence
// (no buffer_wbl2 / buffer_inv) anywhere in the loop. Barrier = distributed:
// 64 parallel slot stores; every block's wave0 polls all 64 slots.
__global__ void __launch_bounds__(256, 1)
lstm_scan(const float* __restrict__ emb, const float* __restrict__ W, const float* __restrict__ bW,
          const float* __restrict__ U, const float* __restrict__ bU,
          const float* __restrict__ V, const float* __restrict__ bV,
          float* __restrict__ out, unsigned char* __restrict__ ws)
{
    const int bid  = blockIdx.x;
    const int cb   = bid & 63;    // column group (16 H-cols)
    const int mb   = bid >> 6;    // batch group == barrier group
    const int tid  = threadIdx.x;
    const int w    = tid >> 6;    // wave id = K-quarter
    const int lane = tid & 63;
    const int fr   = lane & 15;   // frag row/col index
    const int kg   = lane >> 4;   // frag k-block

    u64t* xi_buf = (u64t*)ws;     // [2][64][256] u64 (= [2][64][1024] f16)

    __shared__ __align__(16) float part[4 * 3 * 64 * 4];   // 12 KB
    __shared__ __align__(8) _Float16 xi_tile[16][16];      // 512 B staging
    __shared__ unsigned sE0;

    // per-launch epoch base from OWN slot (only this block writes it)
    if (tid == 0)
        sE0 = __hip_atomic_load(&slotA[mb][cb], __ATOMIC_RELAXED, __HIP_MEMORY_SCOPE_AGENT);
    __syncthreads();
    const unsigned e0 = sE0;

    // ---- persistent weight fragments (f16, registers): 3 gates x 8 ksteps ----
    // B-frag of mfma_f32_16x16x32_f16: lane l holds B[k=(l>>4)*8+e][n=l&15],
    // B[k][n] = Wgate[16*cb + n][k].  (Layout proven rounds 1/4/5/6.)
    half8 Bf[3][8];
    {
        const int jrow = cb * 16 + fr;
        const int kb   = w * 256 + kg * 8;
        const float* p0 = W + jrow * H_ + kb;
        const float* p1 = U + jrow * H_ + kb;
        const float* p2 = V + jrow * H_ + kb;
        #pragma unroll
        for (int ks = 0; ks < 8; ++ks) {
            half8 h0, h1, h2;
            #pragma unroll
            for (int e = 0; e < 8; ++e) {
                h0[e] = (_Float16)p0[ks * 32 + e];
                h1[e] = (_Float16)p1[ks * 32 + e];
                h2[e] = (_Float16)p2[ks * 32 + e];
            }
            Bf[0][ks] = h0; Bf[1][ks] = h1; Bf[2][ks] = h2;
        }
    }

    // ---- elementwise ownership: thread -> ONE cell (b, j) ----
    const int rt = tid >> 4;
    const int ct = tid & 15;
    const int b  = mb * 16 + rt;
    const int j  = cb * 16 + ct;
    const float bw = bW[j], bu = bU[j], bv = bV[j];
    const int rl = (rt >> 2) * 16 + ct;   // C/D source lane (proven)
    const int rr = rt & 3;                // C/D source reg

    // publish xi tile (in LDS) to xi_buf[buf] via 8B sc1 stores, then slot T.
    // tid<64: lane L -> row L>>2, 8B-quarter L&3 of the 16x16 f16 tile.
    auto publish = [&](int buf, unsigned T) {
        __syncthreads();                       // xi_tile complete
        if (tid < 64) {
            const int r  = tid >> 2;
            const int qq = tid & 3;
            u64t v = *(const u64t*)&xi_tile[r][qq * 4];
            __hip_atomic_store(&xi_buf[(unsigned)(buf * 64 * 256 + (mb * 16 + r) * 256 + cb * 4 + qq)],
                               v, __ATOMIC_RELAXED, __HIP_MEMORY_SCOPE_AGENT);
        }
        if (tid == 0) {
            // wave-level: waits ALL wave0 lanes' sc1 stores acked at LLC
            asm volatile("s_waitcnt vmcnt(0)" ::: "memory");
            __hip_atomic_store(&slotA[mb][cb], e0 + T, __ATOMIC_RELAXED,
                               __HIP_MEMORY_SCOPE_AGENT);
        }
    };
    // distributed wait: wave0 polls all 64 slots of the group.
    auto waitall = [&](unsigned T) {
        const unsigned tgt = e0 + T;
        if (tid < 64) {
            for (;;) {
                unsigned v = __hip_atomic_load(&slotA[mb][tid], __ATOMIC_RELAXED,
                                               __HIP_MEMORY_SCOPE_AGENT);
                if (__all((int)(v - tgt) >= 0)) break;
                __builtin_amdgcn_s_sleep(1);
            }
        }
        asm volatile("" ::: "memory");         // no hoisting loads above the poll
        __syncthreads();
    };

    float p1s = 0.0f;
    float xio = emb[(b * S_ + 0) * H_ + j];    // p2 init = 0
    float embn = emb[(b * S_ + 1) * H_ + j];   // prefetch t=1
    xi_tile[rt][ct] = (_Float16)xio;
    publish(0, 1u);
    waitall(1u);

    for (int t = 0; t < S_; ++t) {
        const u64t* xs = xi_buf + (t & 1) * 64 * 256;

        // ---- MFMA: A-frags via 8B sc1 loads (read-around stale L2) ----
        floatx4 a0 = {0.f, 0.f, 0.f, 0.f};
        floatx4 a1 = {0.f, 0.f, 0.f, 0.f};
        floatx4 a2 = {0.f, 0.f, 0.f, 0.f};
        const unsigned abase = (unsigned)((mb * 16 + fr) * 256 + w * 64 + kg * 2);
        #pragma unroll
        for (int ks = 0; ks < 8; ++ks) {
            union { u64t q[2]; half8 h; } cvt;
            cvt.q[0] = __hip_atomic_load(&xs[abase + ks * 8], __ATOMIC_RELAXED,
                                         __HIP_MEMORY_SCOPE_AGENT);
            cvt.q[1] = __hip_atomic_load(&xs[abase + ks * 8 + 1], __ATOMIC_RELAXED,
                                         __HIP_MEMORY_SCOPE_AGENT);
            a0 = __builtin_amdgcn_mfma_f32_16x16x32_f16(cvt.h, Bf[0][ks], a0, 0, 0, 0);
            a1 = __builtin_amdgcn_mfma_f32_16x16x32_f16(cvt.h, Bf[1][ks], a1, 0, 0, 0);
            a2 = __builtin_amdgcn_mfma_f32_16x16x32_f16(cvt.h, Bf[2][ks], a2, 0, 0, 0);
        }

        // ---- K-reduction in LDS ----
        *(floatx4*)&part[((w * 3 + 0) * 64 + lane) * 4] = a0;
        *(floatx4*)&part[((w * 3 + 1) * 64 + lane) * 4] = a1;
        *(floatx4*)&part[((w * 3 + 2) * 64 + lane) * 4] = a2;
        __syncthreads();

        float pf = bw, pu = bu, pv = bv;
        #pragma unroll
        for (int wv = 0; wv < 4; ++wv) {
            pf += part[((wv * 3 + 0) * 64 + rl) * 4 + rr];
            pu += part[((wv * 3 + 1) * 64 + rl) * 4 + rr];
            pv += part[((wv * 3 + 2) * 64 + rl) * 4 + rr];
        }

        // ---- gates + state update ----
        float fg = sigmoidf_(pf);
        float ig = sigmoidf_(pu);
        float gg = tanhf_(pv);
        p1s = fg * p1s + ig * gg;
        float p2 = sigmoidf_(xio) * tanhf_(p1s);
        __builtin_nontemporal_store(p2, &out[(b * S_ + t) * H_ + j]);

        if (t < S_ - 1) {
            float xin = embn + p2;
            xio = xin;
            xi_tile[rt][ct] = (_Float16)xin;
            publish((t + 1) & 1, (unsigned)(t + 2));
            if (t + 2 < S_) embn = emb[(b * S_ + t + 2) * H_ + j];  // overlaps spin
            waitall((unsigned)(t + 2));
        }
    }
}

extern "C" void kernel_launch(void* const* d_in, const int* in_sizes, int n_in,
                              void* d_out, int out_size, void* d_ws, size_t ws_size,
                              hipStream_t stream)
{
    const float* emb = (const float*)d_in[0];
    const float* W   = (const float*)d_in[1];
    const float* bWv = (const float*)d_in[2];
    const float* U   = (const float*)d_in[3];
    const float* bUv = (const float*)d_in[4];
    const float* V   = (const float*)d_in[5];
    const float* bVv = (const float*)d_in[6];
    float* outp = (float*)d_out;
    unsigned char* ws = (unsigned char*)d_ws;
    (void)in_sizes; (void)n_in; (void)out_size; (void)ws_size;

    void* args[] = {(void*)&emb, (void*)&W, (void*)&bWv, (void*)&U, (void*)&bUv,
                    (void*)&V, (void*)&bVv, (void*)&outp, (void*)&ws};
    hipLaunchCooperativeKernel((const void*)lstm_scan, dim3(256), dim3(256),
                               args, 0, stream);
}

// Round 8
// 3393.280 us; speedup vs baseline: 22.8972x; 1.0544x over previous
//
#include <hip/hip_runtime.h>

typedef _Float16 half8 __attribute__((ext_vector_type(8)));
typedef float floatx4 __attribute__((ext_vector_type(4)));
typedef unsigned long long u64t;

#define B_ 64
#define S_ 512
#define H_ 1024

// Arrival slots in module .bss (zero at load; never touched by ws poison).
// Monotonic across launches: every slot advances by exactly S_ per launch.
// Per-launch base e0 = own slot value, read before any arrival (all slots are
// equal at quiescence; only the owning block ever writes its slot).
__device__ unsigned slotA[4][64];

__device__ __forceinline__ float sigmoidf_(float x) { return 1.0f / (1.0f + __expf(-x)); }
__device__ __forceinline__ float tanhf_(float x) {
    return 1.0f - 2.0f / (__expf(2.0f * x) + 1.0f);   // saturates correctly via __expf
}

// 256 blocks x 256 threads (proven cooperative envelope). Block (cb=bid&63,
// mb=bid>>6) owns the 16x16 output tile: batches [16mb,16mb+16) x cols
// [16cb,16cb+16), FULL K=1024; wave = K-quarter; K-reduce in LDS.
// ALL cross-block data (xi) moves via agent-scope relaxed atomics (sc1 path:
// write-through to LLC, read-around the non-coherent L2) -> NO threadfence
// anywhere. Publish: 128 direct 4B stores (lane-paired via shfl_xor), every
// wave drains vmcnt, then tid0 stores its slot. Wait: wave0 polls 64 slots.
__global__ void __launch_bounds__(256, 1)
lstm_scan(const float* __restrict__ emb, const float* __restrict__ W, const float* __restrict__ bW,
          const float* __restrict__ U, const float* __restrict__ bU,
          const float* __restrict__ V, const float* __restrict__ bV,
          float* __restrict__ out, unsigned char* __restrict__ ws)
{
    const int bid  = blockIdx.x;
    const int cb   = bid & 63;    // column group (16 H-cols)
    const int mb   = bid >> 6;    // batch group == barrier group
    const int tid  = threadIdx.x;
    const int w    = tid >> 6;    // wave id = K-quarter
    const int lane = tid & 63;
    const int fr   = lane & 15;   // frag row/col index
    const int kg   = lane >> 4;   // frag k-block

    u64t*     xi64 = (u64t*)ws;      // [2][64][256] u64  (= [2][64][1024] f16)
    unsigned* xi32 = (unsigned*)ws;  // same buffer, u32 view [2][64][512]

    __shared__ __align__(16) float part[4 * 3 * 64 * 4];   // 12 KB
    __shared__ unsigned sE0;

    // per-launch epoch base from OWN slot (only this block writes it)
    if (tid == 0)
        sE0 = __hip_atomic_load(&slotA[mb][cb], __ATOMIC_RELAXED, __HIP_MEMORY_SCOPE_AGENT);
    __syncthreads();
    const unsigned e0 = sE0;

    // ---- persistent weight fragments (f16, registers): 3 gates x 8 ksteps ----
    // B-frag of mfma_f32_16x16x32_f16: lane l holds B[k=(l>>4)*8+e][n=l&15],
    // B[k][n] = Wgate[16*cb + n][k].  (Layout proven rounds 1/4/5/6/7.)
    half8 Bf[3][8];
    {
        const int jrow = cb * 16 + fr;
        const int kb   = w * 256 + kg * 8;
        const float* p0 = W + jrow * H_ + kb;
        const float* p1 = U + jrow * H_ + kb;
        const float* p2 = V + jrow * H_ + kb;
        #pragma unroll
        for (int ks = 0; ks < 8; ++ks) {
            half8 h0, h1, h2;
            #pragma unroll
            for (int e = 0; e < 8; ++e) {
                h0[e] = (_Float16)p0[ks * 32 + e];
                h1[e] = (_Float16)p1[ks * 32 + e];
                h2[e] = (_Float16)p2[ks * 32 + e];
            }
            Bf[0][ks] = h0; Bf[1][ks] = h1; Bf[2][ks] = h2;
        }
    }

    // ---- elementwise ownership: thread -> ONE cell (b, j) ----
    const int rt = tid >> 4;
    const int ct = tid & 15;
    const int b  = mb * 16 + rt;
    const int j  = cb * 16 + ct;
    const float bw = bW[j], bu = bU[j], bv = bV[j];
    const int rl = (rt >> 2) * 16 + ct;   // C/D source lane (proven)
    const int rr = rt & 3;                // C/D source reg
    const bool evenct = (ct & 1) == 0;
    const unsigned pidx = (unsigned)(b * 512 + (j >> 1));  // u32 index (even j)

    // publish xin directly: pair lanes (ct, ct^1) -> one 4B sc1 store by the
    // even lane; ALL waves drain vmcnt (acks at LLC) before the barrier, so
    // the slot store strictly follows every xi store of this block.
    auto publish = [&](int buf, unsigned T, float xin) {
        union { _Float16 h; unsigned short u; } cv;
        cv.h = (_Float16)xin;
        unsigned mine  = cv.u;
        unsigned other = (unsigned)__shfl_xor((int)mine, 1);
        if (evenct)
            __hip_atomic_store(&xi32[(unsigned)(buf * 64 * 512) + pidx],
                               mine | (other << 16), __ATOMIC_RELAXED,
                               __HIP_MEMORY_SCOPE_AGENT);
        asm volatile("s_waitcnt vmcnt(0)" ::: "memory");   // per-wave ack drain
        __syncthreads();
        if (tid == 0)
            __hip_atomic_store(&slotA[mb][cb], e0 + T, __ATOMIC_RELAXED,
                               __HIP_MEMORY_SCOPE_AGENT);
    };
    // distributed wait: wave0 polls all 64 slots of the group.
    auto waitall = [&](unsigned T) {
        const unsigned tgt = e0 + T;
        if (tid < 64) {
            for (;;) {
                unsigned v = __hip_atomic_load(&slotA[mb][tid], __ATOMIC_RELAXED,
                                               __HIP_MEMORY_SCOPE_AGENT);
                if (__all((int)(v - tgt) >= 0)) break;
                __builtin_amdgcn_s_sleep(1);
            }
        }
        asm volatile("" ::: "memory");         // no hoisting loads above the poll
        __syncthreads();
    };

    float p1s = 0.0f;
    float xio = emb[(b * S_ + 0) * H_ + j];    // p2 init = 0
    publish(0, 1u, xio);
    float embn = emb[(b * S_ + 1) * H_ + j];   // prefetch t=1 (overlaps spin)
    waitall(1u);

    for (int t = 0; t < S_; ++t) {
        const u64t* xs = xi64 + (t & 1) * 64 * 256;

        // ---- MFMA: A-frags via 8B sc1 loads (read-around stale L2) ----
        floatx4 a0 = {0.f, 0.f, 0.f, 0.f};
        floatx4 a1 = {0.f, 0.f, 0.f, 0.f};
        floatx4 a2 = {0.f, 0.f, 0.f, 0.f};
        const unsigned abase = (unsigned)((mb * 16 + fr) * 256 + w * 64 + kg * 2);
        #pragma unroll
        for (int ks = 0; ks < 8; ++ks) {
            union { u64t q[2]; half8 h; } cvt;
            cvt.q[0] = __hip_atomic_load(&xs[abase + ks * 8], __ATOMIC_RELAXED,
                                         __HIP_MEMORY_SCOPE_AGENT);
            cvt.q[1] = __hip_atomic_load(&xs[abase + ks * 8 + 1], __ATOMIC_RELAXED,
                                         __HIP_MEMORY_SCOPE_AGENT);
            a0 = __builtin_amdgcn_mfma_f32_16x16x32_f16(cvt.h, Bf[0][ks], a0, 0, 0, 0);
            a1 = __builtin_amdgcn_mfma_f32_16x16x32_f16(cvt.h, Bf[1][ks], a1, 0, 0, 0);
            a2 = __builtin_amdgcn_mfma_f32_16x16x32_f16(cvt.h, Bf[2][ks], a2, 0, 0, 0);
        }

        // ---- K-reduction in LDS ----
        *(floatx4*)&part[((w * 3 + 0) * 64 + lane) * 4] = a0;
        *(floatx4*)&part[((w * 3 + 1) * 64 + lane) * 4] = a1;
        *(floatx4*)&part[((w * 3 + 2) * 64 + lane) * 4] = a2;
        __syncthreads();

        float pf = bw, pu = bu, pv = bv;
        #pragma unroll
        for (int wv = 0; wv < 4; ++wv) {
            pf += part[((wv * 3 + 0) * 64 + rl) * 4 + rr];
            pu += part[((wv * 3 + 1) * 64 + rl) * 4 + rr];
            pv += part[((wv * 3 + 2) * 64 + rl) * 4 + rr];
        }

        // ---- gates + state update ----
        float fg = sigmoidf_(pf);
        float ig = sigmoidf_(pu);
        float gg = tanhf_(pv);
        p1s = fg * p1s + ig * gg;
        float p2 = sigmoidf_(xio) * tanhf_(p1s);

        if (t < S_ - 1) {
            float xin = embn + p2;
            xio = xin;
            publish((t + 1) & 1, (unsigned)(t + 2), xin);
            // after the slot store: these drain during the spin, not before it
            __builtin_nontemporal_store(p2, &out[(b * S_ + t) * H_ + j]);
            if (t + 2 < S_) embn = emb[(b * S_ + t + 2) * H_ + j];
            waitall((unsigned)(t + 2));
        } else {
            __builtin_nontemporal_store(p2, &out[(b * S_ + t) * H_ + j]);
        }
    }
}

extern "C" void kernel_launch(void* const* d_in, const int* in_sizes, int n_in,
                              void* d_out, int out_size, void* d_ws, size_t ws_size,
                              hipStream_t stream)
{
    const float* emb = (const float*)d_in[0];
    const float* W   = (const float*)d_in[1];
    const float* bWv = (const float*)d_in[2];
    const float* U   = (const float*)d_in[3];
    const float* bUv = (const float*)d_in[4];
    const float* V   = (const float*)d_in[5];
    const float* bVv = (const float*)d_in[6];
    float* outp = (float*)d_out;
    unsigned char* ws = (unsigned char*)d_ws;
    (void)in_sizes; (void)n_in; (void)out_size; (void)ws_size;

    void* args[] = {(void*)&emb, (void*)&W, (void*)&bWv, (void*)&U, (void*)&bUv,
                    (void*)&V, (void*)&bVv, (void*)&outp, (void*)&ws};
    hipLaunchCooperativeKernel((const void*)lstm_scan, dim3(256), dim3(256),
                               args, 0, stream);
}

// Round 9
// 2550.630 us; speedup vs baseline: 30.4617x; 1.3304x over previous
//
#include <hip/hip_runtime.h>

typedef _Float16 half8 __attribute__((ext_vector_type(8)));
typedef float floatx4 __attribute__((ext_vector_type(4)));
typedef unsigned long long u64t;

#define B_ 64
#define S_ 512
#define H_ 1024

// Launch epoch base in .bss (zero at load). Block 0 tid 0 bumps it by 1024
// (> S_+1) at kernel END -- provably after every block's start-read of it,
// since block0 finishing its scan requires every block's published data,
// which is published only after that block read tagctr. So all blocks of a
// launch agree on e0, and tags never repeat across launches (stride 1024).
// Poison (0xAAAAAAAA) / zeros never match an expected tag.
__device__ unsigned tagctr;

__device__ __forceinline__ float sigmoidf_(float x) { return 1.0f / (1.0f + __expf(-x)); }
__device__ __forceinline__ float tanhf_(float x) {
    return 1.0f - 2.0f / (__expf(2.0f * x) + 1.0f);   // saturates correctly via __expf
}

// 256 blocks x 256 threads (proven cooperative envelope). Block (cb=bid&63,
// mb=bid>>6) owns the 16x16 output tile: batches [16mb,16mb+16) x cols
// [16cb,16cb+16), FULL K=1024; wave = K-quarter; K-reduce in LDS (24 KB,
// double-buffered -> ONE __syncthreads per step).
//
// NO barrier, NO slots, NO fences: pure tagged-payload dataflow. Publication
// unit = 8 B agent-relaxed atomic word {tag32 | f16 xi[2j], f16 xi[2j+1]}.
// Readers poll exactly the words their MFMA A-fragment needs until the tag
// matches, then consume the payload of the SAME load (atomic 8B => no torn
// tag/data). Double-buffer WAR safety: a block at step t passed its poll =>
// all blocks wrote step t-1 (tag e0+t+1) => (data dependency) all blocks
// finished their step t-1 reads => overwriting buf[(t+1)&1] is safe.
__global__ void __launch_bounds__(256, 1)
lstm_scan(const float* __restrict__ emb, const float* __restrict__ W, const float* __restrict__ bW,
          const float* __restrict__ U, const float* __restrict__ bU,
          const float* __restrict__ V, const float* __restrict__ bV,
          float* __restrict__ out, unsigned char* __restrict__ ws)
{
    const int bid  = blockIdx.x;
    const int cb   = bid & 63;    // column group (16 H-cols)
    const int mb   = bid >> 6;    // batch group (16 batches)
    const int tid  = threadIdx.x;
    const int w    = tid >> 6;    // wave id = K-quarter
    const int lane = tid & 63;
    const int fr   = lane & 15;   // frag row index (A row within tile)
    const int kg   = lane >> 4;   // frag k-block

    u64t* pub = (u64t*)ws;        // [2][64 rows][512 pairs] u64 = 512 KB

    __shared__ __align__(16) float part[2][4 * 3 * 64 * 4];   // 2 x 12 KB

    const unsigned e0 = __hip_atomic_load(&tagctr, __ATOMIC_RELAXED,
                                          __HIP_MEMORY_SCOPE_AGENT);

    // ---- persistent weight fragments (f16, registers): 3 gates x 8 ksteps ----
    // B-frag of mfma_f32_16x16x32_f16: lane l holds B[k=(l>>4)*8+e][n=l&15],
    // B[k][n] = Wgate[16*cb + n][k].  (Layout proven rounds 1/4/5/6/7/8.)
    half8 Bf[3][8];
    {
        const int jrow = cb * 16 + fr;
        const int kb   = w * 256 + kg * 8;
        const float* p0 = W + jrow * H_ + kb;
        const float* p1 = U + jrow * H_ + kb;
        const float* p2 = V + jrow * H_ + kb;
        #pragma unroll
        for (int ks = 0; ks < 8; ++ks) {
            half8 h0, h1, h2;
            #pragma unroll
            for (int e = 0; e < 8; ++e) {
                h0[e] = (_Float16)p0[ks * 32 + e];
                h1[e] = (_Float16)p1[ks * 32 + e];
                h2[e] = (_Float16)p2[ks * 32 + e];
            }
            Bf[0][ks] = h0; Bf[1][ks] = h1; Bf[2][ks] = h2;
        }
    }

    // ---- elementwise ownership: thread -> ONE cell (b, j) ----
    const int rt = tid >> 4;
    const int ct = tid & 15;
    const int b  = mb * 16 + rt;
    const int j  = cb * 16 + ct;
    const float bw = bW[j], bu = bU[j], bv = bV[j];
    const int rl = (rt >> 2) * 16 + ct;   // C/D source lane (proven)
    const int rr = rt & 3;                // C/D source reg
    const bool evenct = (ct & 1) == 0;
    const unsigned widx = (unsigned)(b * 512 + cb * 8 + (ct >> 1));  // pair slot

    // publish own xi value (paired with ct^1 neighbor) as one tagged 8B word.
    auto publish = [&](int buf, unsigned tag, float xin) {
        union { _Float16 h; unsigned short u; } cv;
        cv.h = (_Float16)xin;
        unsigned mine  = cv.u;
        unsigned other = (unsigned)__shfl_xor((int)mine, 1);
        if (evenct)
            __hip_atomic_store(&pub[(unsigned)buf * (64 * 512) + widx],
                               ((u64t)tag << 32) | (u64t)(mine | (other << 16)),
                               __ATOMIC_RELAXED, __HIP_MEMORY_SCOPE_AGENT);
    };

    float p1s = 0.0f;
    float xio = emb[(b * S_ + 0) * H_ + j];    // p2 init = 0
    publish(0, e0 + 1u, xio);
    float embn = emb[(b * S_ + 1) * H_ + j];   // prefetch t=1

    for (int t = 0; t < S_; ++t) {
        const u64t* rowp = pub + (unsigned)(t & 1) * (64 * 512)
                               + (unsigned)(mb * 16 + fr) * 512;
        const unsigned tag   = e0 + (unsigned)t + 1u;
        const unsigned pbase = (unsigned)(w * 128 + kg * 4);

        // ---- poll-consume A-fragments + MFMA (sync IS the data) ----
        floatx4 a0 = {0.f, 0.f, 0.f, 0.f};
        floatx4 a1 = {0.f, 0.f, 0.f, 0.f};
        floatx4 a2 = {0.f, 0.f, 0.f, 0.f};
        #pragma unroll
        for (int ks = 0; ks < 8; ++ks) {
            const unsigned p0 = pbase + (unsigned)ks * 16u;
            u64t q0, q1, q2, q3;
            for (;;) {
                q0 = __hip_atomic_load(&rowp[p0 + 0], __ATOMIC_RELAXED, __HIP_MEMORY_SCOPE_AGENT);
                q1 = __hip_atomic_load(&rowp[p0 + 1], __ATOMIC_RELAXED, __HIP_MEMORY_SCOPE_AGENT);
                q2 = __hip_atomic_load(&rowp[p0 + 2], __ATOMIC_RELAXED, __HIP_MEMORY_SCOPE_AGENT);
                q3 = __hip_atomic_load(&rowp[p0 + 3], __ATOMIC_RELAXED, __HIP_MEMORY_SCOPE_AGENT);
                if ((unsigned)(q0 >> 32) == tag && (unsigned)(q1 >> 32) == tag &&
                    (unsigned)(q2 >> 32) == tag && (unsigned)(q3 >> 32) == tag)
                    break;
                __builtin_amdgcn_s_sleep(1);
            }
            union { unsigned u[4]; half8 h; } cv;
            cv.u[0] = (unsigned)q0; cv.u[1] = (unsigned)q1;
            cv.u[2] = (unsigned)q2; cv.u[3] = (unsigned)q3;
            a0 = __builtin_amdgcn_mfma_f32_16x16x32_f16(cv.h, Bf[0][ks], a0, 0, 0, 0);
            a1 = __builtin_amdgcn_mfma_f32_16x16x32_f16(cv.h, Bf[1][ks], a1, 0, 0, 0);
            a2 = __builtin_amdgcn_mfma_f32_16x16x32_f16(cv.h, Bf[2][ks], a2, 0, 0, 0);
        }

        // ---- K-reduction in LDS (double-buffered -> one sync per step) ----
        float* pp = part[t & 1];
        *(floatx4*)&pp[((w * 3 + 0) * 64 + lane) * 4] = a0;
        *(floatx4*)&pp[((w * 3 + 1) * 64 + lane) * 4] = a1;
        *(floatx4*)&pp[((w * 3 + 2) * 64 + lane) * 4] = a2;
        __syncthreads();

        float pf = bw, pu = bu, pv = bv;
        #pragma unroll
        for (int wv = 0; wv < 4; ++wv) {
            pf += pp[((wv * 3 + 0) * 64 + rl) * 4 + rr];
            pu += pp[((wv * 3 + 1) * 64 + rl) * 4 + rr];
            pv += pp[((wv * 3 + 2) * 64 + rl) * 4 + rr];
        }

        // ---- gates + state update ----
        float fg = sigmoidf_(pf);
        float ig = sigmoidf_(pu);
        float gg = tanhf_(pv);
        p1s = fg * p1s + ig * gg;
        float p2 = sigmoidf_(xio) * tanhf_(p1s);

        if (t < S_ - 1) {
            float xin = embn + p2;
            xio = xin;
            publish((t + 1) & 1, e0 + (unsigned)t + 2u, xin);   // fire and forget
            __builtin_nontemporal_store(p2, &out[(b * S_ + t) * H_ + j]);
            if (t + 2 < S_) embn = emb[(b * S_ + t + 2) * H_ + j];
        } else {
            __builtin_nontemporal_store(p2, &out[(b * S_ + t) * H_ + j]);
        }
    }

    // bump epoch base for the next launch (after all communication done)
    if (bid == 0 && tid == 0)
        __hip_atomic_store(&tagctr, e0 + 1024u, __ATOMIC_RELAXED,
                           __HIP_MEMORY_SCOPE_AGENT);
}

extern "C" void kernel_launch(void* const* d_in, const int* in_sizes, int n_in,
                              void* d_out, int out_size, void* d_ws, size_t ws_size,
                              hipStream_t stream)
{
    const float* emb = (const float*)d_in[0];
    const float* W   = (const float*)d_in[1];
    const float* bWv = (const float*)d_in[2];
    const float* U   = (const float*)d_in[3];
    const float* bUv = (const float*)d_in[4];
    const float* V   = (const float*)d_in[5];
    const float* bVv = (const float*)d_in[6];
    float* outp = (float*)d_out;
    unsigned char* ws = (unsigned char*)d_ws;
    (void)in_sizes; (void)n_in; (void)out_size; (void)ws_size;

    void* args[] = {(void*)&emb, (void*)&W, (void*)&bWv, (void*)&U, (void*)&bUv,
                    (void*)&V, (void*)&bVv, (void*)&outp, (void*)&ws};
    hipLaunchCooperativeKernel((const void*)lstm_scan, dim3(256), dim3(256),
                               args, 0, stream);
}